// Round 4
// baseline (195.913 us; speedup 1.0000x reference)
//
#include <hip/hip_runtime.h>

// out = x @ M^65 @ w_out^T,  M = 0.9 I + 0.1 W  (early-stop provably never fires:
// |eig(M)| in [0.81,0.99] => norm(h)/B stays ~4 orders of magnitude above 1e-6).
// M^65 by repeated squaring in SPLIT-bf16 MFMA (hi+lo, 3 products, fp32 accum).
// All chain GEMMs are no-LDS / no-barrier: MFMA fragments are read DIRECTLY from
// global (L2-resident at this size). Each GEMM stores C row-major AND C^T so the
// next GEMM's B-fragments are k-contiguous 16B loads.
// Final 16384x512x256 GEMM: no-LDS bf16 MFMA, 1024 blocks (4 waves/SIMD),
// in-register fp32->bf16 of x, 2-step register lookahead, zero barriers.

typedef __attribute__((ext_vector_type(4))) float f32x4;
typedef __attribute__((ext_vector_type(8))) short bf16x8;
typedef __attribute__((ext_vector_type(4))) unsigned short u16x4;

__device__ __forceinline__ unsigned short f2bf(float f) {
    unsigned int u = __float_as_uint(f);
    return (unsigned short)((u + 0x7fffu + ((u >> 16) & 1u)) >> 16);  // RNE
}
__device__ __forceinline__ float bf2f(unsigned short h) {
    return __uint_as_float(((unsigned int)h) << 16);
}
__device__ __forceinline__ void split2(float v, unsigned short& h, unsigned short& l) {
    h = f2bf(v);
    l = f2bf(v - bf2f(h));
}

// M = 0.9I + 0.1W, split hi/lo, plus transposed copies (LDS transpose per 32x32 tile).
__global__ __launch_bounds__(256) void build_M(const float* __restrict__ W,
        unsigned short* __restrict__ Mh, unsigned short* __restrict__ Ml,
        unsigned short* __restrict__ MTh, unsigned short* __restrict__ MTl) {
    __shared__ unsigned short Lh[32][40], Ll[32][40];
    const int tid = threadIdx.x, bid = blockIdx.x;
    const int row0 = (bid >> 4) << 5, col0 = (bid & 15) << 5;
    const int r = tid >> 3, c4 = (tid & 7) << 2;
    f32x4 v = *(const f32x4*)&W[(row0 + r) * 512 + col0 + c4];
    u16x4 h4, l4;
    #pragma unroll
    for (int j = 0; j < 4; ++j) {
        float val = 0.1f * v[j];
        if (row0 + r == col0 + c4 + j) val += 0.9f;
        unsigned short hh, ll; split2(val, hh, ll);
        h4[j] = hh; l4[j] = ll;
    }
    *(u16x4*)&Mh[(row0 + r) * 512 + col0 + c4] = h4;
    *(u16x4*)&Ml[(row0 + r) * 512 + col0 + c4] = l4;
    *(u16x4*)&Lh[r][c4] = h4;
    *(u16x4*)&Ll[r][c4] = l4;
    __syncthreads();
    const int c = tid >> 3, rr = (tid & 7) << 2;
    u16x4 th, tl;
    #pragma unroll
    for (int j = 0; j < 4; ++j) { th[j] = Lh[rr + j][c]; tl[j] = Ll[rr + j][c]; }
    *(u16x4*)&MTh[(col0 + c) * 512 + row0 + rr] = th;
    *(u16x4*)&MTl[(col0 + c) * 512 + row0 + rr] = tl;
}

// C[512 x NC] = A @ B, K=512, split-bf16 (3 MFMA), fragments direct from global.
// One 16x16 tile per wave, 4 waves/block, no LDS, no barriers, lookahead-2 pipeline.
// MODE 0 (NC=512): B = BT hi/lo [n][k]; write C hi/lo + C^T hi/lo.  [squarings]
// MODE 1 (NC=256): B = fp32 [n][k] (w_out), split inline; write C^T hi/lo. [Q-fold]
// MODE 2 (NC=256): B = BT hi/lo; write C^T single-bf16 (Pt).        [P-fold]
template<int MODE>
__global__ __launch_bounds__(256) void mm_small(
        const unsigned short* __restrict__ Agh, const unsigned short* __restrict__ Agl,
        const unsigned short* __restrict__ BTh, const unsigned short* __restrict__ BTl,
        const float* __restrict__ Bf,
        unsigned short* __restrict__ Ch, unsigned short* __restrict__ Cl,
        unsigned short* __restrict__ CTh, unsigned short* __restrict__ CTl) {
    const int tid = threadIdx.x, lane = tid & 63, w = tid >> 6;
    const int idx = blockIdx.x * 4 + w;           // one 16x16 tile per wave
    const int l16 = lane & 15, ks = lane >> 4;
    int row0, col0;
    if (MODE == 0) { row0 = (idx >> 5) << 4; col0 = (idx & 31) << 4; }
    else           { row0 = (idx >> 4) << 4; col0 = (idx & 15) << 4; }
    const int aoff = (row0 + l16) * 512 + ks * 8;
    const int boff = (col0 + l16) * 512 + ks * 8;

    f32x4 acc0 = {}, acc1 = {};
    bf16x8 ahX, alX, bhX, blX, ahY, alY, bhY, blY;

    auto LA = [&](int k, bf16x8& ah, bf16x8& al) {
        ah = *(const bf16x8*)&Agh[aoff + k];
        al = *(const bf16x8*)&Agl[aoff + k];
    };
    auto LB = [&](int k, bf16x8& bh, bf16x8& bl) {
        if (MODE == 1) {
            f32x4 v0 = *(const f32x4*)&Bf[boff + k];
            f32x4 v1 = *(const f32x4*)&Bf[boff + k + 4];
            #pragma unroll
            for (int j = 0; j < 4; ++j) {
                unsigned short hh, ll;
                split2(v0[j], hh, ll); bh[j] = (short)hh; bl[j] = (short)ll;
                split2(v1[j], hh, ll); bh[4 + j] = (short)hh; bl[4 + j] = (short)ll;
            }
        } else {
            bh = *(const bf16x8*)&BTh[boff + k];
            bl = *(const bf16x8*)&BTl[boff + k];
        }
    };

    LA(0, ahX, alX);  LB(0, bhX, blX);
    LA(32, ahY, alY); LB(32, bhY, blY);
    #pragma unroll
    for (int t = 0; t < 16; t += 2) {
        acc0 = __builtin_amdgcn_mfma_f32_16x16x32_bf16(ahX, bhX, acc0, 0, 0, 0);
        acc1 = __builtin_amdgcn_mfma_f32_16x16x32_bf16(ahX, blX, acc1, 0, 0, 0);
        acc1 = __builtin_amdgcn_mfma_f32_16x16x32_bf16(alX, bhX, acc1, 0, 0, 0);
        if (t + 2 < 16) { LA((t + 2) * 32, ahX, alX); LB((t + 2) * 32, bhX, blX); }
        acc0 = __builtin_amdgcn_mfma_f32_16x16x32_bf16(ahY, bhY, acc0, 0, 0, 0);
        acc1 = __builtin_amdgcn_mfma_f32_16x16x32_bf16(ahY, blY, acc1, 0, 0, 0);
        acc1 = __builtin_amdgcn_mfma_f32_16x16x32_bf16(alY, bhY, acc1, 0, 0, 0);
        if (t + 3 < 16) { LA((t + 3) * 32, ahY, alY); LB((t + 3) * 32, bhY, blY); }
    }

    const int orow = row0 + ks * 4;   // C/D: col = lane&15, row = (lane>>4)*4 + j
    const int ocol = col0 + l16;
    float cv[4];
    #pragma unroll
    for (int j = 0; j < 4; ++j) cv[j] = acc0[j] + acc1[j];
    if (MODE == 2) {
        u16x4 t4;
        #pragma unroll
        for (int j = 0; j < 4; ++j) t4[j] = f2bf(cv[j]);
        *(u16x4*)&CTh[ocol * 512 + orow] = t4;
    } else {
        u16x4 th4, tl4;
        #pragma unroll
        for (int j = 0; j < 4; ++j) {
            unsigned short hh, ll; split2(cv[j], hh, ll);
            th4[j] = hh; tl4[j] = ll;
            if (MODE == 0) {
                Ch[(orow + j) * 512 + ocol] = hh;
                Cl[(orow + j) * 512 + ocol] = ll;
            }
        }
        *(u16x4*)&CTh[ocol * 512 + orow] = th4;
        *(u16x4*)&CTl[ocol * 512 + orow] = tl4;
    }
}

// out[16384 x 256] = X (fp32 -> bf16 in-register) @ P; Pt bf16 [256][512] = P^T.
// 16-row tile per block, 1024 blocks (4/CU -> 4 waves/SIMD), 4 waves cover all 256
// cols (64 each). No LDS, no barriers: A-frags direct from X (waves share rows ->
// L1 hits), B-frags direct from L2-resident Pt. 2-phase register lookahead.
__global__ __launch_bounds__(256) void gemm_big(const float* __restrict__ X,
        const unsigned short* __restrict__ Pt, float* __restrict__ out) {
    const int tid = threadIdx.x, lane = tid & 63, w = tid >> 6;
    const int l16 = lane & 15, ks = lane >> 4;
    const int row0 = blockIdx.x << 4;
    const float* xp = X + (row0 + l16) * 512 + ks * 8;
    const unsigned short* bp = Pt + (w * 64 + l16) * 512 + ks * 8;

    f32x4 acc[4] = {};
    f32x4 a0X, a1X, a0Y, a1Y;
    bf16x8 bX[4], bY[4];

    a0X = *(const f32x4*)xp;        a1X = *(const f32x4*)(xp + 4);
    #pragma unroll
    for (int n = 0; n < 4; ++n) bX[n] = *(const bf16x8*)&bp[n * 8192];
    a0Y = *(const f32x4*)(xp + 32); a1Y = *(const f32x4*)(xp + 36);
    #pragma unroll
    for (int n = 0; n < 4; ++n) bY[n] = *(const bf16x8*)&bp[32 + n * 8192];

    #pragma unroll
    for (int t = 0; t < 16; t += 2) {
        bf16x8 af;
        #pragma unroll
        for (int j = 0; j < 4; ++j) { af[j] = (short)f2bf(a0X[j]); af[4 + j] = (short)f2bf(a1X[j]); }
        #pragma unroll
        for (int n = 0; n < 4; ++n)
            acc[n] = __builtin_amdgcn_mfma_f32_16x16x32_bf16(af, bX[n], acc[n], 0, 0, 0);
        if (t + 2 < 16) {
            a0X = *(const f32x4*)(xp + (t + 2) * 32);
            a1X = *(const f32x4*)(xp + (t + 2) * 32 + 4);
            #pragma unroll
            for (int n = 0; n < 4; ++n) bX[n] = *(const bf16x8*)&bp[(t + 2) * 32 + n * 8192];
        }
        bf16x8 ag;
        #pragma unroll
        for (int j = 0; j < 4; ++j) { ag[j] = (short)f2bf(a0Y[j]); ag[4 + j] = (short)f2bf(a1Y[j]); }
        #pragma unroll
        for (int n = 0; n < 4; ++n)
            acc[n] = __builtin_amdgcn_mfma_f32_16x16x32_bf16(ag, bY[n], acc[n], 0, 0, 0);
        if (t + 3 < 16) {
            a0Y = *(const f32x4*)(xp + (t + 3) * 32);
            a1Y = *(const f32x4*)(xp + (t + 3) * 32 + 4);
            #pragma unroll
            for (int n = 0; n < 4; ++n) bY[n] = *(const bf16x8*)&bp[(t + 3) * 32 + n * 8192];
        }
    }

    #pragma unroll
    for (int n = 0; n < 4; ++n)
        #pragma unroll
        for (int j = 0; j < 4; ++j)
            out[(row0 + ks * 4 + j) * 256 + w * 64 + n * 16 + l16] = acc[n][j];
}

extern "C" void kernel_launch(void* const* d_in, const int* in_sizes, int n_in,
                              void* d_out, int out_size, void* d_ws, size_t ws_size,
                              hipStream_t stream) {
    const float* x     = (const float*)d_in[0];   // 16384 x 512
    const float* W     = (const float*)d_in[1];   // 512 x 512
    const float* w_out = (const float*)d_in[2];   // 256 x 512
    float* out = (float*)d_out;                   // 16384 x 256
    unsigned short* u = (unsigned short*)d_ws;

    const size_t SZ = 512 * 512;
    unsigned short *S0h = u,          *S0l = u + SZ,     *S0Th = u + 2 * SZ, *S0Tl = u + 3 * SZ;
    unsigned short *S1h = u + 4 * SZ, *S1l = u + 5 * SZ, *S1Th = u + 6 * SZ, *S1Tl = u + 7 * SZ;
    unsigned short *QTh = u + 8 * SZ;             // 256*512
    unsigned short *QTl = QTh + 131072;
    unsigned short *Ptb = QTl + 131072;           // 256*512 bf16 = P^T

    dim3 blk(256);
    build_M<<<256, blk, 0, stream>>>(W, S0h, S0l, S0Th, S0Tl);
    // Q = M @ w_out^T (must precede overwriting of S0 — reads only S0*)
    mm_small<1><<<128, blk, 0, stream>>>(S0h, S0l, nullptr, nullptr, w_out,
                                         nullptr, nullptr, QTh, QTl);
    mm_small<0><<<256, blk, 0, stream>>>(S0h, S0l, S0Th, S0Tl, nullptr, S1h, S1l, S1Th, S1Tl); // M^2
    mm_small<0><<<256, blk, 0, stream>>>(S1h, S1l, S1Th, S1Tl, nullptr, S0h, S0l, S0Th, S0Tl); // M^4
    mm_small<0><<<256, blk, 0, stream>>>(S0h, S0l, S0Th, S0Tl, nullptr, S1h, S1l, S1Th, S1Tl); // M^8
    mm_small<0><<<256, blk, 0, stream>>>(S1h, S1l, S1Th, S1Tl, nullptr, S0h, S0l, S0Th, S0Tl); // M^16
    mm_small<0><<<256, blk, 0, stream>>>(S0h, S0l, S0Th, S0Tl, nullptr, S1h, S1l, S1Th, S1Tl); // M^32
    mm_small<0><<<256, blk, 0, stream>>>(S1h, S1l, S1Th, S1Tl, nullptr, S0h, S0l, S0Th, S0Tl); // M^64
    mm_small<2><<<128, blk, 0, stream>>>(S0h, S0l, QTh, QTl, nullptr,
                                         nullptr, nullptr, Ptb, nullptr);  // Pt = (M^64 @ Q)^T
    gemm_big<<<1024, blk, 0, stream>>>(x, Ptb, out);                        // out = x @ P
}

// Round 5
// 137.746 us; speedup vs baseline: 1.4223x; 1.4223x over previous
//
#include <hip/hip_runtime.h>

// out = x @ M^65 @ w_out^T,  M = 0.9 I + 0.1 W  (early-stop provably never fires:
// |eig(M)| in [0.81,0.99] => norm(h)/B stays ~4 orders above 1e-6 for all 65 steps).
// M^65 via repeated squaring in SPLIT-bf16 MFMA (hi+lo, 3 products, fp32 accum).
// All GEMMs: global_load_lds(16B) staging + counted vmcnt + raw s_barrier pipeline.
// LDS bank conflicts avoided by XOR-swizzle, applied BOTH sides (pre-swizzled
// global source feeding linear gld_lds dest + swizzled ds_read).

typedef __attribute__((ext_vector_type(4))) float f32x4;
typedef __attribute__((ext_vector_type(8))) short bf16x8;
typedef __attribute__((ext_vector_type(4))) unsigned short u16x4;

typedef __attribute__((address_space(1))) const unsigned int guint;
typedef __attribute__((address_space(3))) unsigned int luint;

__device__ __forceinline__ void gld_lds16(const void* g, void* l) {
    __builtin_amdgcn_global_load_lds((guint*)g, (luint*)l, 16, 0, 0);
}

__device__ __forceinline__ unsigned short f2bf(float f) {
    unsigned int u = __float_as_uint(f);
    return (unsigned short)((u + 0x7fffu + ((u >> 16) & 1u)) >> 16);  // RNE
}
__device__ __forceinline__ float bf2f(unsigned short h) {
    return __uint_as_float(((unsigned int)h) << 16);
}
__device__ __forceinline__ void split2(float v, unsigned short& h, unsigned short& l) {
    h = f2bf(v);
    l = f2bf(v - bf2f(h));
}

// ---- M = 0.9I + 0.1W, split hi/lo, plus transposed copies (proven round 3) ----
__global__ __launch_bounds__(256) void build_M(const float* __restrict__ W,
        unsigned short* __restrict__ Mh, unsigned short* __restrict__ Ml,
        unsigned short* __restrict__ MTh, unsigned short* __restrict__ MTl) {
    __shared__ unsigned short Lh[32][40], Ll[32][40];
    const int tid = threadIdx.x, bid = blockIdx.x;
    const int row0 = (bid >> 4) << 5, col0 = (bid & 15) << 5;
    const int r = tid >> 3, c4 = (tid & 7) << 2;
    f32x4 v = *(const f32x4*)&W[(row0 + r) * 512 + col0 + c4];
    u16x4 h4, l4;
    #pragma unroll
    for (int j = 0; j < 4; ++j) {
        float val = 0.1f * v[j];
        if (row0 + r == col0 + c4 + j) val += 0.9f;
        unsigned short hh, ll; split2(val, hh, ll);
        h4[j] = hh; l4[j] = ll;
    }
    *(u16x4*)&Mh[(row0 + r) * 512 + col0 + c4] = h4;
    *(u16x4*)&Ml[(row0 + r) * 512 + col0 + c4] = l4;
    *(u16x4*)&Lh[r][c4] = h4;
    *(u16x4*)&Ll[r][c4] = l4;
    __syncthreads();
    const int c = tid >> 3, rr = (tid & 7) << 2;
    u16x4 th, tl;
    #pragma unroll
    for (int j = 0; j < 4; ++j) { th[j] = Lh[rr + j][c]; tl[j] = Ll[rr + j][c]; }
    *(u16x4*)&MTh[(col0 + c) * 512 + row0 + rr] = th;
    *(u16x4*)&MTl[(col0 + c) * 512 + row0 + rr] = tl;
}

// ---- split w_out (256x512 fp32) into hi/lo bf16 (already B^T layout) ----
__global__ __launch_bounds__(256) void wsplit(const float* __restrict__ w,
        unsigned short* __restrict__ WOh, unsigned short* __restrict__ WOl) {
    const int i4 = (blockIdx.x * 256 + threadIdx.x) * 4;   // 131072 elems
    f32x4 v = *(const f32x4*)&w[i4];
    u16x4 h4, l4;
    #pragma unroll
    for (int j = 0; j < 4; ++j) { unsigned short hh, ll; split2(v[j], hh, ll); h4[j] = hh; l4[j] = ll; }
    *(u16x4*)&WOh[i4] = h4;
    *(u16x4*)&WOl[i4] = l4;
}

// ---- chain GEMM: C[512 x NC] = A @ B, K=512, split-bf16 (3 MFMA / k-slot) ----
// A row-major hi/lo; B as B^T rows [n][k] hi/lo. 32x32 block tile, 2x2 waves of
// 16x16. gld_lds staging (4 arrays), XOR-swizzled, vmcnt(4)-counted, raw barriers.
// OUTMODE 0: write C hi/lo + C^T hi/lo (squarings); 1: C^T hi/lo (Q-fold);
// OUTMODE 2: C^T single bf16 (P-fold).
template<int NC, int OUTMODE>
__global__ __launch_bounds__(256) void chain_mm2(
        const unsigned short* __restrict__ Agh, const unsigned short* __restrict__ Agl,
        const unsigned short* __restrict__ BTh, const unsigned short* __restrict__ BTl,
        unsigned short* __restrict__ Ch, unsigned short* __restrict__ Cl,
        unsigned short* __restrict__ CTh, unsigned short* __restrict__ CTl) {
    __shared__ unsigned short SB[2][4][32][64];   // [buf][Ah Al Bh Bl][row][k]
    const int tid = threadIdx.x, lane = tid & 63, w = tid >> 6;
    const int wr = w >> 1, wc = w & 1;
    const int l16 = lane & 15, ks = lane >> 4;
    const int row0 = (NC == 512 ? (blockIdx.x >> 4) : (blockIdx.x >> 3)) << 5;
    const int col0 = (NC == 512 ? (blockIdx.x & 15) : (blockIdx.x & 7)) << 5;

    // staging: thread covers LDS bytes [tid*16, +16) of each array (wave-uniform
    // base + lane*16). Source pre-swizzled: row = tid>>3, byte-col ^ ((row&7)<<4).
    const int srow = tid >> 3;
    const int ssw  = ((tid & 7) << 4) ^ ((srow & 7) << 4);
    const unsigned short* aghp = Agh + (row0 + srow) * 512 + (ssw >> 1);
    const unsigned short* aglp = Agl + (row0 + srow) * 512 + (ssw >> 1);
    const unsigned short* bthp = BTh + (col0 + srow) * 512 + (ssw >> 1);
    const unsigned short* btlp = BTl + (col0 + srow) * 512 + (ssw >> 1);

    f32x4 acc0 = {}, acc1 = {};

    #define CH_STAGE(buf, t) {                                        \
        const int k_ = (t) << 6;                                      \
        char* d_ = (char*)SB[buf][0] + tid * 16;                      \
        gld_lds16(aghp + k_, d_);                                     \
        gld_lds16(aglp + k_, d_ + 4096);                              \
        gld_lds16(bthp + k_, d_ + 8192);                              \
        gld_lds16(btlp + k_, d_ + 12288);                             \
    }

    CH_STAGE(0, 0);
    #pragma unroll
    for (int t = 0; t < 8; ++t) {
        const int buf = t & 1;
        if (t < 7) CH_STAGE(buf ^ 1, t + 1);
        if (t < 7) asm volatile("s_waitcnt vmcnt(4)" ::: "memory");
        else       asm volatile("s_waitcnt vmcnt(0)" ::: "memory");
        __builtin_amdgcn_sched_barrier(0);
        __builtin_amdgcn_s_barrier();

        const int sw = (l16 & 7) << 4;
        const int ra = (wr * 16 + l16) * 128;   // A row byte base
        const int rb = (wc * 16 + l16) * 128;   // B^T row byte base
        #pragma unroll
        for (int s = 0; s < 2; ++s) {
            const int qa = (ra + s * 64 + ks * 16) ^ sw;
            const int qb = (rb + s * 64 + ks * 16) ^ sw;
            bf16x8 ah = *(const bf16x8*)((const char*)SB[buf][0] + qa);
            bf16x8 al = *(const bf16x8*)((const char*)SB[buf][1] + qa);
            bf16x8 bh = *(const bf16x8*)((const char*)SB[buf][2] + qb);
            bf16x8 bl = *(const bf16x8*)((const char*)SB[buf][3] + qb);
            acc0 = __builtin_amdgcn_mfma_f32_16x16x32_bf16(ah, bh, acc0, 0, 0, 0);
            acc1 = __builtin_amdgcn_mfma_f32_16x16x32_bf16(ah, bl, acc1, 0, 0, 0);
            acc1 = __builtin_amdgcn_mfma_f32_16x16x32_bf16(al, bh, acc1, 0, 0, 0);
        }
        __builtin_amdgcn_s_barrier();
    }
    #undef CH_STAGE

    const int orow = row0 + wr * 16 + ks * 4;   // C/D: col=lane&15, row=(lane>>4)*4+j
    const int ocol = col0 + wc * 16 + l16;
    float cv[4];
    #pragma unroll
    for (int j = 0; j < 4; ++j) cv[j] = acc0[j] + acc1[j];
    if (OUTMODE == 2) {
        u16x4 t4;
        #pragma unroll
        for (int j = 0; j < 4; ++j) t4[j] = f2bf(cv[j]);
        *(u16x4*)&CTh[ocol * 512 + orow] = t4;
    } else {
        u16x4 th4, tl4;
        #pragma unroll
        for (int j = 0; j < 4; ++j) {
            unsigned short hh, ll; split2(cv[j], hh, ll);
            th4[j] = hh; tl4[j] = ll;
            if (OUTMODE == 0) {
                Ch[(orow + j) * 512 + ocol] = hh;
                Cl[(orow + j) * 512 + ocol] = ll;
            }
        }
        *(u16x4*)&CTh[ocol * 512 + orow] = th4;
        *(u16x4*)&CTl[ocol * 512 + orow] = tl4;
    }
}

// ---- out[16384 x 256] = X @ P.  Pt bf16 [256][512] = P^T (L2-resident). ----
// BM=32, BN=256 (4 waves x 64 cols), BK=64, grid 512 (2 blocks/CU). X staged fp32
// via gld_lds with pre-swizzled source; B-frags direct from L2, lookahead-1;
// vmcnt(10)-counted pipeline, raw barriers, fp32->bf16 at frag read.
__global__ __launch_bounds__(256, 2) void gemm_final(const float* __restrict__ X,
        const unsigned short* __restrict__ Pt, float* __restrict__ out) {
    __shared__ float XS[2][32][64];               // 8 KB per buffer, swizzled layout
    const int tid = threadIdx.x, lane = tid & 63, w = tid >> 6;
    const int l16 = lane & 15, ks = lane >> 4;
    const int row0 = blockIdx.x << 5;

    // staging: inst i covers LDS bytes i*4096 + tid*16 -> row = i*16 + (tid>>4),
    // byte-col = (tid&15)*16; source k-byte = col ^ ((row&7)<<4)
    const int srow = tid >> 4;
    const int scs  = (((tid & 15) << 4) ^ ((srow & 7) << 4)) >> 2;   // float offset
    const float* xp0 = X + (row0 + srow) * 512 + scs;
    const float* xp1 = X + (row0 + 16 + srow) * 512 + scs;           // (row&7) same
    const unsigned short* bp = Pt + (w * 64 + l16) * 512 + ks * 8;

    f32x4 acc[2][4] = {};
    bf16x8 Breg[2][8];

    #define FG_STAGE(buf, t) {                                       \
        const int k_ = (t) << 6;                                     \
        gld_lds16(xp0 + k_, (char*)XS[buf] + tid * 16);              \
        gld_lds16(xp1 + k_, (char*)XS[buf] + 4096 + tid * 16);       \
    }
    #define FG_LOADB(set, t) {                                       \
        const int k_ = (t) << 6;                                     \
        _Pragma("unroll")                                            \
        for (int n = 0; n < 4; ++n)                                  \
            _Pragma("unroll")                                        \
            for (int s = 0; s < 2; ++s)                              \
                Breg[set][n * 2 + s] =                               \
                    *(const bf16x8*)&bp[n * 8192 + k_ + s * 32];     \
    }

    FG_STAGE(0, 0);
    FG_LOADB(0, 0);
    #pragma unroll
    for (int t = 0; t < 8; ++t) {
        const int buf = t & 1;
        if (t < 7) { FG_STAGE(buf ^ 1, t + 1); FG_LOADB(buf ^ 1, t + 1); }
        if (t < 7) asm volatile("s_waitcnt vmcnt(10)" ::: "memory");
        else       asm volatile("s_waitcnt vmcnt(0)" ::: "memory");
        __builtin_amdgcn_sched_barrier(0);
        __builtin_amdgcn_s_barrier();

        const int sw = (l16 & 7) << 4;
        #pragma unroll
        for (int m = 0; m < 2; ++m) {
            bf16x8 af[2];
            #pragma unroll
            for (int s = 0; s < 2; ++s) {
                const int q = (m * 16 + l16) * 256 + s * 128 + ks * 32;
                f32x4 v0 = *(const f32x4*)((const char*)XS[buf] + (q ^ sw));
                f32x4 v1 = *(const f32x4*)((const char*)XS[buf] + ((q + 16) ^ sw));
                #pragma unroll
                for (int j = 0; j < 4; ++j) {
                    af[s][j]     = (short)f2bf(v0[j]);
                    af[s][4 + j] = (short)f2bf(v1[j]);
                }
            }
            #pragma unroll
            for (int n = 0; n < 4; ++n) {
                acc[m][n] = __builtin_amdgcn_mfma_f32_16x16x32_bf16(af[0], Breg[buf][n * 2 + 0], acc[m][n], 0, 0, 0);
                acc[m][n] = __builtin_amdgcn_mfma_f32_16x16x32_bf16(af[1], Breg[buf][n * 2 + 1], acc[m][n], 0, 0, 0);
            }
        }
        __builtin_amdgcn_s_barrier();
    }
    #undef FG_STAGE
    #undef FG_LOADB

    #pragma unroll
    for (int m = 0; m < 2; ++m)
        #pragma unroll
        for (int n = 0; n < 4; ++n)
            #pragma unroll
            for (int j = 0; j < 4; ++j)
                out[(row0 + m * 16 + ks * 4 + j) * 256 + w * 64 + n * 16 + l16] = acc[m][n][j];
}

extern "C" void kernel_launch(void* const* d_in, const int* in_sizes, int n_in,
                              void* d_out, int out_size, void* d_ws, size_t ws_size,
                              hipStream_t stream) {
    const float* x     = (const float*)d_in[0];   // 16384 x 512
    const float* W     = (const float*)d_in[1];   // 512 x 512
    const float* w_out = (const float*)d_in[2];   // 256 x 512
    float* out = (float*)d_out;                   // 16384 x 256
    unsigned short* u = (unsigned short*)d_ws;

    const size_t SZ = 512 * 512, HZ = 256 * 512;
    unsigned short *S0h = u,          *S0l = u + SZ,     *S0Th = u + 2 * SZ, *S0Tl = u + 3 * SZ;
    unsigned short *S1h = u + 4 * SZ, *S1l = u + 5 * SZ, *S1Th = u + 6 * SZ, *S1Tl = u + 7 * SZ;
    unsigned short *QTh = u + 8 * SZ, *QTl = QTh + HZ, *Ptb = QTl + HZ;
    unsigned short *WOh = Ptb + HZ,   *WOl = WOh + HZ;

    dim3 blk(256);
    wsplit <<<128, blk, 0, stream>>>(w_out, WOh, WOl);
    build_M<<<256, blk, 0, stream>>>(W, S0h, S0l, S0Th, S0Tl);
    // Q = M @ w_out^T (reads S0 only; must precede sq2 which overwrites S0)
    chain_mm2<256, 1><<<128, blk, 0, stream>>>(S0h, S0l, WOh, WOl, nullptr, nullptr, QTh, QTl);
    chain_mm2<512, 0><<<256, blk, 0, stream>>>(S0h, S0l, S0Th, S0Tl, S1h, S1l, S1Th, S1Tl); // M^2
    chain_mm2<512, 0><<<256, blk, 0, stream>>>(S1h, S1l, S1Th, S1Tl, S0h, S0l, S0Th, S0Tl); // M^4
    chain_mm2<512, 0><<<256, blk, 0, stream>>>(S0h, S0l, S0Th, S0Tl, S1h, S1l, S1Th, S1Tl); // M^8
    chain_mm2<512, 0><<<256, blk, 0, stream>>>(S1h, S1l, S1Th, S1Tl, S0h, S0l, S0Th, S0Tl); // M^16
    chain_mm2<512, 0><<<256, blk, 0, stream>>>(S0h, S0l, S0Th, S0Tl, S1h, S1l, S1Th, S1Tl); // M^32
    chain_mm2<512, 0><<<256, blk, 0, stream>>>(S1h, S1l, S1Th, S1Tl, S0h, S0l, S0Th, S0Tl); // M^64
    chain_mm2<256, 2><<<128, blk, 0, stream>>>(S0h, S0l, QTh, QTl, nullptr, nullptr, Ptb, nullptr); // Pt
    gemm_final<<<512, blk, 0, stream>>>(x, Ptb, out);
}